// Round 10
// baseline (224.755 us; speedup 1.0000x reference)
//
#include <hip/hip_runtime.h>
#include <math.h>

#define B_  16
#define C_  64
#define E_  5

typedef __bf16  bf16x8 __attribute__((ext_vector_type(8)));
typedef float   f32x4  __attribute__((ext_vector_type(4)));
typedef unsigned int u32x4 __attribute__((ext_vector_type(4)));

// ---- ws byte offsets ----
// wEffB: [e(5)][g(2)][tap(9)][q(4)][co(64)][j(8)] ushort = 184320 shorts = 368640 B
#define WS_WEFFB   0
#define WS_BIAS    368640       // float[5*64] -> 369920
#define WS_POOL    369920       // float[16*64] (zeroed) -> 374016
#define WS_Z       374016       // float[16] (zeroed) -> 374080
#define WS_CNT     374080       // (unused, layout stability) -> 376128
#define WS_XT      376128       // bf16 x_t [b][row][col][ci] = 33554432 B -> 33930560
#define WS_EXP     33930560ull  // bf16 exp [b][co][row][col] -> 67484992
#define WS_NEED_A  67484992ull

static __device__ __forceinline__ unsigned short f2bf(float f) {
    unsigned int u = __float_as_uint(f);
    unsigned int r = (u + 0x7fffu + ((u >> 16) & 1u)) >> 16;  // RNE
    return (unsigned short)r;
}

// ---------------------------------------------------------------------------
// Kernel 1: blocks 0..2047: fused transpose (fp32 NCHW -> bf16 NHWC) + pooling
//           blocks 2048+  : build effective weights + biases   [known-good]
__global__ __launch_bounds__(256) void transpose_build_kernel(
        const float* __restrict__ x, unsigned short* __restrict__ x_t,
        float* __restrict__ pooled,
        const float* __restrict__ w1, const float* __restrict__ w_cd,
        const float* __restrict__ w_hd, const float* __restrict__ w_vd,
        const float* __restrict__ w_ad,
        const float* __restrict__ b1, const float* __restrict__ b_cd,
        const float* __restrict__ b_hd, const float* __restrict__ b_vd,
        const float* __restrict__ b_ad,
        unsigned short* __restrict__ wEffB, float* __restrict__ biasEff) {
    int bid = blockIdx.x;
    int t = threadIdx.x;

    if (bid >= 2048) {
        int gid = (bid - 2048) * 256 + t;
        if (gid < E_ * 36864) {
            int e   = gid / 36864;
            int r   = gid % 36864;
            int g   = r / 18432;
            int r2  = r % 18432;
            int tap = r2 / 2048;
            int r3  = r2 % 2048;
            int q   = r3 / 512;
            int r4  = r3 % 512;
            int co  = r4 / 8;
            int j   = r4 % 8;
            int ci = g * 32 + q * 8 + j;
            int base9 = (co * 64 + ci) * 9;
            int base3 = (co * 64 + ci) * 3;
            float v = 0.f;
            if (e == 0) {
                v = w1[base9 + tap];
            } else if (e == 1) {
                if (tap == 4) {
                    float s = 0.f;
                    #pragma unroll
                    for (int k = 0; k < 9; k++) s += w_cd[base9 + k];
                    v = w_cd[base9 + 4] - s;
                } else {
                    v = w_cd[base9 + tap];
                }
            } else if (e == 2) {
                int m = tap % 3;
                if (m == 0) v = w_hd[base3 + tap / 3];
                else if (m == 2) v = -w_hd[base3 + tap / 3];
            } else if (e == 3) {
                if (tap < 3) v = w_vd[base3 + tap];
                else if (tap >= 6) v = -w_vd[base3 + tap - 6];
            } else {
                const int PERM[9] = {3, 0, 1, 6, 4, 2, 7, 8, 5};
                v = w_ad[base9 + tap] - w_ad[base9 + PERM[tap]];
            }
            wEffB[gid] = f2bf(v);
        } else if (gid < E_ * 36864 + E_ * 64) {
            int jj = gid - E_ * 36864;
            int e = jj / 64, co = jj % 64;
            const float* bs;
            switch (e) {
                case 0: bs = b1; break;
                case 1: bs = b_cd; break;
                case 2: bs = b_hd; break;
                case 3: bs = b_vd; break;
                default: bs = b_ad; break;
            }
            biasEff[jj] = bs[co];
        }
        return;
    }

    int b = bid >> 7, row = bid & 127;
    int wave = t >> 6, l = t & 63;
    int half = l >> 5;
    int c4 = l & 31;

    __shared__ unsigned short T[128][72];

    const float* xb = x + (size_t)b * (64 * 16384) + row * 128;

    #pragma unroll
    for (int it = 0; it < 8; it++) {
        int ci = wave * 16 + it * 2 + half;
        float4 v = *(const float4*)(xb + (size_t)ci * 16384 + c4 * 4);
        float p = v.x + v.y + v.z + v.w;
        p += __shfl_down(p, 16, 32);
        p += __shfl_down(p, 8, 32);
        p += __shfl_down(p, 4, 32);
        p += __shfl_down(p, 2, 32);
        p += __shfl_down(p, 1, 32);
        if (c4 == 0) atomicAdd(&pooled[b * 64 + ci], p * (1.0f / 16384.0f));
        int colb = c4 * 4;
        T[colb + 0][ci] = f2bf(v.x);
        T[colb + 1][ci] = f2bf(v.y);
        T[colb + 2][ci] = f2bf(v.z);
        T[colb + 3][ci] = f2bf(v.w);
    }
    __syncthreads();

    unsigned short* dst = x_t + ((size_t)(b * 128 + row) * 128) * 64;
    #pragma unroll
    for (int k = 0; k < 4; k++) {
        int chunk = t + k * 256;
        int col = chunk >> 3, c8 = chunk & 7;
        uint4 vv = *(const uint4*)&T[col][c8 * 8];
        *(uint4*)(dst + col * 64 + c8 * 8) = vv;
    }
}

// ---------------------------------------------------------------------------
// Kernel 2: MFMA implicit-GEMM conv + exp + store + per-example Z sum
// grid: b(16) x rowgroup(32) x colhalf(2) = 1024 blocks, 256 thr (4 waves)
// R4 staging structure (best measured, 45.8us): X full 6-row tile per g,
// A in 3-tap chunks -- PLUS T14 async-stage: A chunk c+1 is prefetched into
// registers (3x uint4) while chunk c's MFMAs run, hiding the L2 latency that
// was previously exposed after each barrier. setprio(1) around the MFMA
// cluster (4 independent blocks/CU = phase diversity, T5 regime).
__global__ __launch_bounds__(256, 4) void conv_mfma_kernel(
        const unsigned short* __restrict__ x_t, const unsigned short* __restrict__ wEffB,
        const float* __restrict__ biasEff,
        const float* __restrict__ pooled, const float* __restrict__ noise,
        const float* __restrict__ w_gate, const float* __restrict__ b_gate,
        const float* __restrict__ w_noise, const float* __restrict__ b_noise,
        unsigned short* __restrict__ expw, float* __restrict__ outf,
        float* __restrict__ Z, int direct_f32) {
    int bid = blockIdx.x;
    int b = bid >> 6;
    int rem = bid & 63;
    int rg = rem >> 1;        // 0..31, out rows rg*4..+3
    int ch = rem & 1;         // 0/1,  out cols ch*64..+63

    int t = threadIdx.x;
    int wave = t >> 6;        // out-row-local 0..3
    int lane = t & 63;
    int ln = lane & 15;
    int q = lane >> 4;

    __shared__ __align__(16) unsigned short A_lds[3 * 4 * 66 * 8];  // 12672 B
    __shared__ __align__(16) unsigned short Xs[6 * 4 * 68 * 8];     // 26112 B
    __shared__ float zs[4];
    __shared__ int   se_sh;

    // ---- inline routing (wave 0), identical FP sequence to prep kernel ----
    if (wave == 0) {
        float pv = pooled[b * C_ + lane];
        float ge[E_], ne[E_];
        #pragma unroll
        for (int e = 0; e < E_; e++) {
            ge[e] = pv * w_gate[lane * E_ + e];
            ne[e] = pv * w_noise[lane * E_ + e];
        }
        #pragma unroll
        for (int off = 32; off; off >>= 1) {
            #pragma unroll
            for (int e = 0; e < E_; e++) {
                ge[e] += __shfl_xor(ge[e], off, 64);
                ne[e] += __shfl_xor(ne[e], off, 64);
            }
        }
        if (lane == 0) {
            float best = -1e30f; int bi = 0;
            #pragma unroll
            for (int e = 0; e < E_; e++) {
                float lg = ge[e] + b_gate[e];
                float nz = ne[e] + b_noise[e];
                float sp = log1pf(expf(nz));
                float v = lg + noise[b * E_ + e] * sp;
                if (v > best) { best = v; bi = e; }   // first max wins (matches top_k)
            }
            se_sh = bi;
        }
    }
    __syncthreads();
    int e = se_sh;

    f32x4 acc[4][4];
    #pragma unroll
    for (int i = 0; i < 4; i++)
        #pragma unroll
        for (int jn = 0; jn < 4; jn++)
            acc[i][jn] = (f32x4){0.f, 0.f, 0.f, 0.f};

    const unsigned short* xb = x_t + (size_t)b * (128 * 128 * 64);
    const unsigned short* we = wEffB + (size_t)e * 36864;
    const uint4* asrc0 = (const uint4*)we;            // g=0: chunks 0..2 (768 ea)
    const uint4* asrc1 = (const uint4*)(we + 18432);  // g=1

    // per-thread A-write address components: reg k -> slotrow (t>>6)+4k, m = t&63
    int awrow = t >> 6, awm = t & 63;

    // prefetch A chunk 0 of g=0 (latency hides under X staging below)
    uint4 a0 = asrc0[t], a1 = asrc0[t + 256], a2 = asrc0[t + 512];

    for (int g = 0; g < 2; g++) {
        // --- stage X: 6 rows x 66 cols x (4 q-chunks of 8 ci) ---
        for (int j = t; j < 1584; j += 256) {
            int xr = j / 264;
            int r2 = j % 264;
            int col = r2 >> 2;
            int qq = r2 & 3;
            int irow = rg * 4 - 1 + xr;
            int icol = ch * 64 - 1 + col;
            uint4 v = make_uint4(0, 0, 0, 0);
            if ((unsigned)irow < 128u && (unsigned)icol < 128u)
                v = *(const uint4*)(xb + ((size_t)irow * 128 + icol) * 64 + g * 32 + qq * 8);
            *(uint4*)&Xs[((xr * 4 + qq) * 68 + col) * 8] = v;
        }

        #pragma unroll
        for (int chunk = 0; chunk < 3; chunk++) {
            // --- write prefetched A regs -> LDS ---
            *(uint4*)&A_lds[((awrow     ) * 66 + awm) * 8] = a0;
            *(uint4*)&A_lds[((awrow +  4) * 66 + awm) * 8] = a1;
            *(uint4*)&A_lds[((awrow +  8) * 66 + awm) * 8] = a2;
            __syncthreads();    // A chunk (and, for chunk 0, X) visible

            // --- issue prefetch of NEXT chunk (hidden under MFMAs below) ---
            int nc = g * 3 + chunk + 1;            // linear next chunk 1..6
            if (nc < 6) {
                const uint4* an = (nc < 3) ? (asrc0 + nc * 768)
                                           : (asrc1 + (nc - 3) * 768);
                a0 = an[t]; a1 = an[t + 256]; a2 = an[t + 512];
            }

            // taps chunk*3 .. chunk*3+2: dr = chunk, dc = tl
            int xr = wave + chunk;
            __builtin_amdgcn_s_setprio(1);
            #pragma unroll
            for (int tl = 0; tl < 3; tl++) {
                bf16x8 af[4], bfr[4];
                #pragma unroll
                for (int mt = 0; mt < 4; mt++)
                    af[mt] = *(const bf16x8*)&A_lds[((tl * 4 + q) * 66 + mt * 16 + ln) * 8];
                #pragma unroll
                for (int t4 = 0; t4 < 4; t4++)
                    bfr[t4] = *(const bf16x8*)&Xs[((xr * 4 + q) * 68 + t4 * 16 + ln + tl) * 8];
                #pragma unroll
                for (int mt = 0; mt < 4; mt++)
                    #pragma unroll
                    for (int t4 = 0; t4 < 4; t4++)
                        acc[mt][t4] = __builtin_amdgcn_mfma_f32_16x16x32_bf16(
                            af[mt], bfr[t4], acc[mt][t4], 0, 0, 0);
            }
            __builtin_amdgcn_s_setprio(0);
            __syncthreads();    // WAR: compute done before next A write / X stage
        }
    }

    // --- epilogue: bias + exp + store + Z reduction ---
    int orow = rg * 4 + wave;
    float bsum = 0.f;
    size_t obase = (size_t)b * (64 * 16384);
    #pragma unroll
    for (int mt = 0; mt < 4; mt++) {
        float4 bias4 = *(const float4*)(biasEff + e * 64 + mt * 16 + q * 4);
        const float* bp = (const float*)&bias4;
        #pragma unroll
        for (int r = 0; r < 4; r++) {
            int co = mt * 16 + q * 4 + r;
            size_t cb = obase + (size_t)co * 16384 + (size_t)orow * 128;
            #pragma unroll
            for (int t4 = 0; t4 < 4; t4++) {
                float ev = __expf(acc[mt][t4][r] + bp[r]);
                bsum += ev;
                int ocol = ch * 64 + t4 * 16 + ln;
                if (direct_f32) outf[cb + ocol] = ev;
                else            expw[cb + ocol] = f2bf(ev);
            }
        }
    }
    for (int off = 32; off; off >>= 1) bsum += __shfl_down(bsum, off, 64);
    if (lane == 0) zs[wave] = bsum;
    __syncthreads();
    if (t == 0) atomicAdd(&Z[b], zs[0] + zs[1] + zs[2] + zs[3]);
}

// ---------------------------------------------------------------------------
// Kernel 3a: out = bf16_exp * (1/Z[b]) -> fp32 (Mode A), grid-stride 2048 blocks
// nontemporal: expw is read exactly once; out is written once.
#define N_UINT4 2097152   // 16 * 64 * 16384 / 8
__global__ __launch_bounds__(256) void scale_bf16_kernel(
        const unsigned short* __restrict__ expw, const float* __restrict__ Z,
        float* __restrict__ out) {
    __shared__ float sinv[B_];
    if (threadIdx.x < B_) sinv[threadIdx.x] = 1.0f / Z[threadIdx.x];
    __syncthreads();
    for (int gid = blockIdx.x * 256 + threadIdx.x; gid < N_UINT4; gid += 2048 * 256) {
        int b = gid >> 17;
        float s = sinv[b];
        u32x4 r = __builtin_nontemporal_load(&((const u32x4*)expw)[gid]);
        f32x4 o0, o1;
        o0[0] = __uint_as_float(r[0] << 16) * s;
        o0[1] = __uint_as_float(r[0] & 0xffff0000u) * s;
        o0[2] = __uint_as_float(r[1] << 16) * s;
        o0[3] = __uint_as_float(r[1] & 0xffff0000u) * s;
        o1[0] = __uint_as_float(r[2] << 16) * s;
        o1[1] = __uint_as_float(r[2] & 0xffff0000u) * s;
        o1[2] = __uint_as_float(r[3] << 16) * s;
        o1[3] = __uint_as_float(r[3] & 0xffff0000u) * s;
        __builtin_nontemporal_store(o0, &((f32x4*)out)[gid * 2]);
        __builtin_nontemporal_store(o1, &((f32x4*)out)[gid * 2 + 1]);
    }
}

// Kernel 3b: in-place out *= 1/Z[b] (Mode B), grid-stride
#define N_FLOAT4 4194304
__global__ __launch_bounds__(256) void scale_inplace_kernel(
        float* __restrict__ out, const float* __restrict__ Z) {
    __shared__ float sinv[B_];
    if (threadIdx.x < B_) sinv[threadIdx.x] = 1.0f / Z[threadIdx.x];
    __syncthreads();
    for (int gid = blockIdx.x * 256 + threadIdx.x; gid < N_FLOAT4; gid += 2048 * 256) {
        int b = gid >> 18;
        float s = sinv[b];
        float4 v = ((float4*)out)[gid];
        v.x *= s; v.y *= s; v.z *= s; v.w *= s;
        ((float4*)out)[gid] = v;
    }
}

// ---------------------------------------------------------------------------
extern "C" void kernel_launch(void* const* d_in, const int* in_sizes, int n_in,
                              void* d_out, int out_size, void* d_ws, size_t ws_size,
                              hipStream_t stream) {
    const float* x       = (const float*)d_in[0];
    const float* noise   = (const float*)d_in[1];
    const float* w_gate  = (const float*)d_in[2];
    const float* b_gate  = (const float*)d_in[3];
    const float* w_noise = (const float*)d_in[4];
    const float* b_noise = (const float*)d_in[5];
    const float* w1      = (const float*)d_in[6];
    const float* b1      = (const float*)d_in[7];
    const float* w_cd    = (const float*)d_in[8];
    const float* b_cd    = (const float*)d_in[9];
    const float* w_hd    = (const float*)d_in[10];
    const float* b_hd    = (const float*)d_in[11];
    const float* w_vd    = (const float*)d_in[12];
    const float* b_vd    = (const float*)d_in[13];
    const float* w_ad    = (const float*)d_in[14];
    const float* b_ad    = (const float*)d_in[15];

    char* ws = (char*)d_ws;
    unsigned short* wEffB   = (unsigned short*)(ws + WS_WEFFB);
    float*          biasEff = (float*)(ws + WS_BIAS);
    float*          pooled  = (float*)(ws + WS_POOL);
    float*          Zbuf    = (float*)(ws + WS_Z);
    unsigned short* x_t     = (unsigned short*)(ws + WS_XT);
    unsigned short* expw    = (unsigned short*)(ws + WS_EXP);

    float* out = (float*)d_out;
    int mode_a = (ws_size >= WS_NEED_A) ? 1 : 0;

    // zero pooled + Z (contiguous 4160 B)
    hipMemsetAsync(pooled, 0, 4160, stream);

    transpose_build_kernel<<<2048 + 722, 256, 0, stream>>>(
        x, x_t, pooled, w1, w_cd, w_hd, w_vd, w_ad,
        b1, b_cd, b_hd, b_vd, b_ad, wEffB, biasEff);

    conv_mfma_kernel<<<1024, 256, 0, stream>>>(
        x_t, wEffB, biasEff, pooled, noise, w_gate, b_gate, w_noise, b_noise,
        expw, out, Zbuf, mode_a ? 0 : 1);

    if (mode_a)
        scale_bf16_kernel<<<2048, 256, 0, stream>>>(expw, Zbuf, out);
    else
        scale_inplace_kernel<<<2048, 256, 0, stream>>>(out, Zbuf);
}

// Round 11
// 220.816 us; speedup vs baseline: 1.0178x; 1.0178x over previous
//
#include <hip/hip_runtime.h>
#include <math.h>

#define B_  16
#define C_  64
#define E_  5

typedef __bf16  bf16x8 __attribute__((ext_vector_type(8)));
typedef float   f32x4  __attribute__((ext_vector_type(4)));
typedef unsigned int u32x4 __attribute__((ext_vector_type(4)));

// ---- ws byte offsets ----
// wEffB: [e(5)][g(2)][tap(9)][q(4)][co(64)][j(8)] ushort = 184320 shorts = 368640 B
#define WS_WEFFB   0
#define WS_BIAS    368640       // float[5*64] -> 369920
#define WS_POOL    369920       // float[16*64] (zeroed) -> 374016
#define WS_Z       374016       // float[16] (zeroed) -> 374080
#define WS_CNT     374080       // uint[16*32] padded counters (zeroed) -> 376128
#define WS_XT      376128       // bf16 x_t [b][row][col][ci] = 33554432 B -> 33930560
#define WS_EXP     33930560ull  // bf16 exp (fallback path only) -> 67484992
#define WS_NEED_A  67484992ull

static __device__ __forceinline__ unsigned short f2bf(float f) {
    unsigned int u = __float_as_uint(f);
    unsigned int r = (u + 0x7fffu + ((u >> 16) & 1u)) >> 16;  // RNE
    return (unsigned short)r;
}

// ---------------------------------------------------------------------------
// Kernel 1: blocks 0..2047: fused transpose (fp32 NCHW -> bf16 NHWC) + pooling
//           blocks 2048+  : build effective weights + biases   [known-good]
__global__ __launch_bounds__(256) void transpose_build_kernel(
        const float* __restrict__ x, unsigned short* __restrict__ x_t,
        float* __restrict__ pooled,
        const float* __restrict__ w1, const float* __restrict__ w_cd,
        const float* __restrict__ w_hd, const float* __restrict__ w_vd,
        const float* __restrict__ w_ad,
        const float* __restrict__ b1, const float* __restrict__ b_cd,
        const float* __restrict__ b_hd, const float* __restrict__ b_vd,
        const float* __restrict__ b_ad,
        unsigned short* __restrict__ wEffB, float* __restrict__ biasEff) {
    int bid = blockIdx.x;
    int t = threadIdx.x;

    if (bid >= 2048) {
        int gid = (bid - 2048) * 256 + t;
        if (gid < E_ * 36864) {
            int e   = gid / 36864;
            int r   = gid % 36864;
            int g   = r / 18432;
            int r2  = r % 18432;
            int tap = r2 / 2048;
            int r3  = r2 % 2048;
            int q   = r3 / 512;
            int r4  = r3 % 512;
            int co  = r4 / 8;
            int j   = r4 % 8;
            int ci = g * 32 + q * 8 + j;
            int base9 = (co * 64 + ci) * 9;
            int base3 = (co * 64 + ci) * 3;
            float v = 0.f;
            if (e == 0) {
                v = w1[base9 + tap];
            } else if (e == 1) {
                if (tap == 4) {
                    float s = 0.f;
                    #pragma unroll
                    for (int k = 0; k < 9; k++) s += w_cd[base9 + k];
                    v = w_cd[base9 + 4] - s;
                } else {
                    v = w_cd[base9 + tap];
                }
            } else if (e == 2) {
                int m = tap % 3;
                if (m == 0) v = w_hd[base3 + tap / 3];
                else if (m == 2) v = -w_hd[base3 + tap / 3];
            } else if (e == 3) {
                if (tap < 3) v = w_vd[base3 + tap];
                else if (tap >= 6) v = -w_vd[base3 + tap - 6];
            } else {
                const int PERM[9] = {3, 0, 1, 6, 4, 2, 7, 8, 5};
                v = w_ad[base9 + tap] - w_ad[base9 + PERM[tap]];
            }
            wEffB[gid] = f2bf(v);
        } else if (gid < E_ * 36864 + E_ * 64) {
            int jj = gid - E_ * 36864;
            int e = jj / 64, co = jj % 64;
            const float* bs;
            switch (e) {
                case 0: bs = b1; break;
                case 1: bs = b_cd; break;
                case 2: bs = b_hd; break;
                case 3: bs = b_vd; break;
                default: bs = b_ad; break;
            }
            biasEff[jj] = bs[co];
        }
        return;
    }

    int b = bid >> 7, row = bid & 127;
    int wave = t >> 6, l = t & 63;
    int half = l >> 5;
    int c4 = l & 31;

    __shared__ unsigned short T[128][72];

    const float* xb = x + (size_t)b * (64 * 16384) + row * 128;

    #pragma unroll
    for (int it = 0; it < 8; it++) {
        int ci = wave * 16 + it * 2 + half;
        float4 v = *(const float4*)(xb + (size_t)ci * 16384 + c4 * 4);
        float p = v.x + v.y + v.z + v.w;
        p += __shfl_down(p, 16, 32);
        p += __shfl_down(p, 8, 32);
        p += __shfl_down(p, 4, 32);
        p += __shfl_down(p, 2, 32);
        p += __shfl_down(p, 1, 32);
        if (c4 == 0) atomicAdd(&pooled[b * 64 + ci], p * (1.0f / 16384.0f));
        int colb = c4 * 4;
        T[colb + 0][ci] = f2bf(v.x);
        T[colb + 1][ci] = f2bf(v.y);
        T[colb + 2][ci] = f2bf(v.z);
        T[colb + 3][ci] = f2bf(v.w);
    }
    __syncthreads();

    unsigned short* dst = x_t + ((size_t)(b * 128 + row) * 128) * 64;
    #pragma unroll
    for (int k = 0; k < 4; k++) {
        int chunk = t + k * 256;
        int col = chunk >> 3, c8 = chunk & 7;
        uint4 vv = *(const uint4*)&T[col][c8 * 8];
        *(uint4*)(dst + col * 64 + c8 * 8) = vv;
    }
}

// ---------------------------------------------------------------------------
// Kernel 2: MFMA implicit-GEMM conv + exp + per-batch barrier + scaled store
// grid: b(16) x rowgroup(32) x colhalf(2) = 1024 blocks, 256 thr (4 waves)
// Conv body = R9's ring structure EXACTLY (passed, 49.5us, VGPR 64, no spill):
// X = 4-row ring (17.4 KB), A = 3-tap chunks (12.7 KB), LDS 30208 B ->
// 5 blocks/CU capacity = 1280 > 1024 grid (256 slots slack -> no deadlock;
// R7's hang was the 38.9KB/4-per-CU EXACT-fit variant). Barrier epilogue =
// R5's (passed on HW at this capacity): Z atomic -> cnt arrive -> spin ->
// in-register scale -> f32 out. Deletes the scale dispatch (-64 MB traffic).
// __launch_bounds__(256,4): VGPR cap 128 (R5's (256,5)->96 caused the spill).
__global__ __launch_bounds__(256, 4) void conv_mfma_kernel(
        const unsigned short* __restrict__ x_t, const unsigned short* __restrict__ wEffB,
        const float* __restrict__ biasEff,
        const float* __restrict__ pooled, const float* __restrict__ noise,
        const float* __restrict__ w_gate, const float* __restrict__ b_gate,
        const float* __restrict__ w_noise, const float* __restrict__ b_noise,
        unsigned short* __restrict__ expw, float* __restrict__ outf,
        float* __restrict__ Z, unsigned int* __restrict__ cnt,
        int do_bar, int direct_f32) {
    int bid = blockIdx.x;
    int b = bid >> 6;
    int rem = bid & 63;
    int rg = rem >> 1;        // 0..31, out rows rg*4..+3
    int ch = rem & 1;         // 0/1,  out cols ch*64..+63

    int t = threadIdx.x;
    int wave = t >> 6;        // out-row-local 0..3
    int lane = t & 63;
    int ln = lane & 15;
    int q = lane >> 4;

    __shared__ __align__(16) unsigned short A_lds[3 * 4 * 66 * 8];  // 12672 B
    __shared__ __align__(16) unsigned short Xs[4 * 4 * 68 * 8];     // 17408 B (4-row ring)
    __shared__ float zs[4];
    __shared__ int   se_sh;
    __shared__ float sinv_sh;

    // ---- inline routing (wave 0), identical FP sequence to prep kernel ----
    if (wave == 0) {
        float pv = pooled[b * C_ + lane];
        float ge[E_], ne[E_];
        #pragma unroll
        for (int e = 0; e < E_; e++) {
            ge[e] = pv * w_gate[lane * E_ + e];
            ne[e] = pv * w_noise[lane * E_ + e];
        }
        #pragma unroll
        for (int off = 32; off; off >>= 1) {
            #pragma unroll
            for (int e = 0; e < E_; e++) {
                ge[e] += __shfl_xor(ge[e], off, 64);
                ne[e] += __shfl_xor(ne[e], off, 64);
            }
        }
        if (lane == 0) {
            float best = -1e30f; int bi = 0;
            #pragma unroll
            for (int e = 0; e < E_; e++) {
                float lg = ge[e] + b_gate[e];
                float nz = ne[e] + b_noise[e];
                float sp = log1pf(expf(nz));
                float v = lg + noise[b * E_ + e] * sp;
                if (v > best) { best = v; bi = e; }   // first max wins (matches top_k)
            }
            se_sh = bi;
        }
    }
    __syncthreads();
    int e = se_sh;

    f32x4 acc[4][4];
    #pragma unroll
    for (int i = 0; i < 4; i++)
        #pragma unroll
        for (int jn = 0; jn < 4; jn++)
            acc[i][jn] = (f32x4){0.f, 0.f, 0.f, 0.f};

    const unsigned short* xb = x_t + (size_t)b * (128 * 128 * 64);
    const unsigned short* we = wEffB + (size_t)e * 36864;

    for (int g = 0; g < 2; g++) {
        const uint4* asrc = (const uint4*)(we + g * 18432);
        #pragma unroll
        for (int chunk = 0; chunk < 3; chunk++) {
            // --- stage X rows into 4-slot ring (slot = xr & 3) ---
            if (chunk == 0) {
                for (int j = t; j < 1056; j += 256) {
                    int xr = j / 264;                 // 0..3
                    int r2 = j % 264;
                    int col = r2 >> 2;
                    int qq = r2 & 3;
                    int irow = rg * 4 - 1 + xr;
                    int icol = ch * 64 - 1 + col;
                    uint4 v = make_uint4(0, 0, 0, 0);
                    if ((unsigned)irow < 128u && (unsigned)icol < 128u)
                        v = *(const uint4*)(xb + ((size_t)irow * 128 + icol) * 64 + g * 32 + qq * 8);
                    *(uint4*)&Xs[(((xr & 3) * 4 + qq) * 68 + col) * 8] = v;
                }
            } else {
                int xr = 3 + chunk;                   // 4 or 5
                int irow = rg * 4 - 1 + xr;
                for (int j = t; j < 264; j += 256) {
                    int col = j >> 2;
                    int qq = j & 3;
                    int icol = ch * 64 - 1 + col;
                    uint4 v = make_uint4(0, 0, 0, 0);
                    if ((unsigned)irow < 128u && (unsigned)icol < 128u)
                        v = *(const uint4*)(xb + ((size_t)irow * 128 + icol) * 64 + g * 32 + qq * 8);
                    *(uint4*)&Xs[(((xr & 3) * 4 + qq) * 68 + col) * 8] = v;
                }
            }
            // --- stage A chunk: 3 taps = 768 x 16B ([tap_local][q][co][j]) ---
            #pragma unroll
            for (int k = 0; k < 3; k++) {
                int j = t + k * 256;                  // 0..767
                int slotrow = j >> 6;                 // tap_local*4 + q
                int m = j & 63;
                *(uint4*)&A_lds[(slotrow * 66 + m) * 8] = asrc[chunk * 768 + j];
            }
            __syncthreads();

            // taps chunk*3 .. chunk*3+2: dr = chunk, dc = tl
            int xrl = wave + chunk;
            #pragma unroll
            for (int tl = 0; tl < 3; tl++) {
                bf16x8 af[4], bfr[4];
                #pragma unroll
                for (int mt = 0; mt < 4; mt++)
                    af[mt] = *(const bf16x8*)&A_lds[((tl * 4 + q) * 66 + mt * 16 + ln) * 8];
                #pragma unroll
                for (int t4 = 0; t4 < 4; t4++)
                    bfr[t4] = *(const bf16x8*)&Xs[(((xrl & 3) * 4 + q) * 68 + t4 * 16 + ln + tl) * 8];
                #pragma unroll
                for (int mt = 0; mt < 4; mt++)
                    #pragma unroll
                    for (int t4 = 0; t4 < 4; t4++)
                        acc[mt][t4] = __builtin_amdgcn_mfma_f32_16x16x32_bf16(
                            af[mt], bfr[t4], acc[mt][t4], 0, 0, 0);
            }
            __syncthreads();    // WAR: compute done before next stage overwrites
        }
    }

    // --- epilogue: bias + exp (kept in acc) + Z reduction ---
    float bsum = 0.f;
    #pragma unroll
    for (int mt = 0; mt < 4; mt++) {
        float4 bias4 = *(const float4*)(biasEff + e * 64 + mt * 16 + q * 4);
        const float* bp = (const float*)&bias4;
        #pragma unroll
        for (int r = 0; r < 4; r++) {
            #pragma unroll
            for (int t4 = 0; t4 < 4; t4++) {
                float ev = __expf(acc[mt][t4][r] + bp[r]);
                acc[mt][t4][r] = ev;
                bsum += ev;
            }
        }
    }
    for (int off = 32; off; off >>= 1) bsum += __shfl_down(bsum, off, 64);
    if (lane == 0) zs[wave] = bsum;
    __syncthreads();

    int orow = rg * 4 + wave;
    size_t obase = (size_t)b * (64 * 16384);

    if (do_bar) {
        // ---- per-batch barrier: 64 co-resident blocks arrive, then scale ----
        if (t == 0) {
            atomicAdd(&Z[b], zs[0] + zs[1] + zs[2] + zs[3]);
            __threadfence();
            atomicAdd(&cnt[b * 32], 1u);
            unsigned int it = 0;
            while (__hip_atomic_load(&cnt[b * 32], __ATOMIC_RELAXED,
                                     __HIP_MEMORY_SCOPE_AGENT) < 64u) {
                __builtin_amdgcn_s_sleep(8);
                if (++it > (1u << 20)) break;     // escape valve: never hang
            }
            __threadfence();
            sinv_sh = 1.0f / __hip_atomic_load(&Z[b], __ATOMIC_RELAXED,
                                               __HIP_MEMORY_SCOPE_AGENT);
        }
        __syncthreads();
        float sinv = sinv_sh;
        #pragma unroll
        for (int mt = 0; mt < 4; mt++) {
            #pragma unroll
            for (int r = 0; r < 4; r++) {
                int co = mt * 16 + q * 4 + r;
                size_t cb = obase + (size_t)co * 16384 + (size_t)orow * 128;
                #pragma unroll
                for (int t4 = 0; t4 < 4; t4++) {
                    int ocol = ch * 64 + t4 * 16 + ln;
                    outf[cb + ocol] = acc[mt][t4][r] * sinv;
                }
            }
        }
    } else {
        // ---- fallback: store unscaled exp, host runs scale kernel ----
        if (t == 0) atomicAdd(&Z[b], zs[0] + zs[1] + zs[2] + zs[3]);
        #pragma unroll
        for (int mt = 0; mt < 4; mt++) {
            #pragma unroll
            for (int r = 0; r < 4; r++) {
                int co = mt * 16 + q * 4 + r;
                size_t cb = obase + (size_t)co * 16384 + (size_t)orow * 128;
                #pragma unroll
                for (int t4 = 0; t4 < 4; t4++) {
                    int ocol = ch * 64 + t4 * 16 + ln;
                    float ev = acc[mt][t4][r];
                    if (direct_f32) outf[cb + ocol] = ev;
                    else            expw[cb + ocol] = f2bf(ev);
                }
            }
        }
    }
}

// ---------------------------------------------------------------------------
// Fallback scale kernels (launched only when the barrier path is rejected)
#define N_UINT4 2097152   // 16 * 64 * 16384 / 8
__global__ __launch_bounds__(256) void scale_bf16_kernel(
        const unsigned short* __restrict__ expw, const float* __restrict__ Z,
        float* __restrict__ out) {
    __shared__ float sinv[B_];
    if (threadIdx.x < B_) sinv[threadIdx.x] = 1.0f / Z[threadIdx.x];
    __syncthreads();
    for (int gid = blockIdx.x * 256 + threadIdx.x; gid < N_UINT4; gid += 2048 * 256) {
        int b = gid >> 17;
        float s = sinv[b];
        u32x4 r = __builtin_nontemporal_load(&((const u32x4*)expw)[gid]);
        f32x4 o0, o1;
        o0[0] = __uint_as_float(r[0] << 16) * s;
        o0[1] = __uint_as_float(r[0] & 0xffff0000u) * s;
        o0[2] = __uint_as_float(r[1] << 16) * s;
        o0[3] = __uint_as_float(r[1] & 0xffff0000u) * s;
        o1[0] = __uint_as_float(r[2] << 16) * s;
        o1[1] = __uint_as_float(r[2] & 0xffff0000u) * s;
        o1[2] = __uint_as_float(r[3] << 16) * s;
        o1[3] = __uint_as_float(r[3] & 0xffff0000u) * s;
        __builtin_nontemporal_store(o0, &((f32x4*)out)[gid * 2]);
        __builtin_nontemporal_store(o1, &((f32x4*)out)[gid * 2 + 1]);
    }
}

#define N_FLOAT4 4194304
__global__ __launch_bounds__(256) void scale_inplace_kernel(
        float* __restrict__ out, const float* __restrict__ Z) {
    __shared__ float sinv[B_];
    if (threadIdx.x < B_) sinv[threadIdx.x] = 1.0f / Z[threadIdx.x];
    __syncthreads();
    for (int gid = blockIdx.x * 256 + threadIdx.x; gid < N_FLOAT4; gid += 2048 * 256) {
        int b = gid >> 18;
        float s = sinv[b];
        float4 v = ((float4*)out)[gid];
        v.x *= s; v.y *= s; v.z *= s; v.w *= s;
        ((float4*)out)[gid] = v;
    }
}

// ---------------------------------------------------------------------------
extern "C" void kernel_launch(void* const* d_in, const int* in_sizes, int n_in,
                              void* d_out, int out_size, void* d_ws, size_t ws_size,
                              hipStream_t stream) {
    const float* x       = (const float*)d_in[0];
    const float* noise   = (const float*)d_in[1];
    const float* w_gate  = (const float*)d_in[2];
    const float* b_gate  = (const float*)d_in[3];
    const float* w_noise = (const float*)d_in[4];
    const float* b_noise = (const float*)d_in[5];
    const float* w1      = (const float*)d_in[6];
    const float* b1      = (const float*)d_in[7];
    const float* w_cd    = (const float*)d_in[8];
    const float* b_cd    = (const float*)d_in[9];
    const float* w_hd    = (const float*)d_in[10];
    const float* b_hd    = (const float*)d_in[11];
    const float* w_vd    = (const float*)d_in[12];
    const float* b_vd    = (const float*)d_in[13];
    const float* w_ad    = (const float*)d_in[14];
    const float* b_ad    = (const float*)d_in[15];

    char* ws = (char*)d_ws;
    unsigned short* wEffB   = (unsigned short*)(ws + WS_WEFFB);
    float*          biasEff = (float*)(ws + WS_BIAS);
    float*          pooled  = (float*)(ws + WS_POOL);
    float*          Zbuf    = (float*)(ws + WS_Z);
    unsigned int*   cnt     = (unsigned int*)(ws + WS_CNT);
    unsigned short* x_t     = (unsigned short*)(ws + WS_XT);
    unsigned short* expw    = (unsigned short*)(ws + WS_EXP);

    float* out = (float*)d_out;

    // zero pooled + Z + cnt (contiguous 6208 B)
    hipMemsetAsync(pooled, 0, 6208, stream);

    // barrier path requires residency slack: LDS 30208 -> 5 blocks/CU ->
    // capacity 1280 > grid 1024. Gate on the runtime's own occupancy math.
    int nb = 0;
    hipError_t qerr = hipOccupancyMaxActiveBlocksPerMultiprocessor(
        &nb, (const void*)conv_mfma_kernel, 256, 0);
    int do_bar = (qerr == hipSuccess && nb >= 5) ? 1 : 0;
    int mode_a = (ws_size >= WS_NEED_A) ? 1 : 0;

    transpose_build_kernel<<<2048 + 722, 256, 0, stream>>>(
        x, x_t, pooled, w1, w_cd, w_hd, w_vd, w_ad,
        b1, b_cd, b_hd, b_vd, b_ad, wEffB, biasEff);

    conv_mfma_kernel<<<1024, 256, 0, stream>>>(
        x_t, wEffB, biasEff, pooled, noise, w_gate, b_gate, w_noise, b_noise,
        expw, out, Zbuf, cnt, do_bar, (do_bar || !mode_a) ? 1 : 0);

    if (!do_bar) {
        if (mode_a)
            scale_bf16_kernel<<<2048, 256, 0, stream>>>(expw, Zbuf, out);
        else
            scale_inplace_kernel<<<2048, 256, 0, stream>>>(out, Zbuf);
    }
}